// Round 1
// baseline (347.368 us; speedup 1.0000x reference)
//
#include <hip/hip_runtime.h>
#include <hip/hip_bf16.h>

#define N_RAYS 262144
#define N_PTS  64
#define FAR_DELTA 1e10f
#define RAYS_PER_BLOCK 4   // 256 threads = 4 waves, 1 wave per ray

__global__ __launch_bounds__(256) void volume_render_kernel(
    const float* __restrict__ density,       // (N, 64, 1)
    const float* __restrict__ depth_values,  // (N, 64)
    const float* __restrict__ rays_feature,  // (N, 64, 3)
    float* __restrict__ out)                 // feature (N*3) then depth (N)
{
    const int wave = threadIdx.x >> 6;
    const int lane = threadIdx.x & 63;
    const int ray  = blockIdx.x * RAYS_PER_BLOCK + wave;
    if (ray >= N_RAYS) return;

    const long base = (long)ray * N_PTS;

    // Coalesced loads: lane i <-> sample i
    const float d_i  = depth_values[base + lane];
    const float sig  = density[base + lane];

    // delta_i = depth[i+1] - depth[i]; last sample gets the far sentinel
    float d_next = __shfl_down(d_i, 1, 64);
    float delta  = (lane == 63) ? FAR_DELTA : (d_next - d_i);
    float sd     = sig * delta;   // sigma * delta (lane 63 may be ~1e10)

    // Inclusive prefix sum of sd across the wave (6 shuffle steps)
    float s = sd;
    #pragma unroll
    for (int off = 1; off < 64; off <<= 1) {
        float t = __shfl_up(s, off, 64);
        if (lane >= off) s += t;
    }
    // Exclusive prefix: shift inclusive up one lane. Lane 63's inclusive
    // value (contains the 1e10 sentinel) is never consumed, so the huge
    // sentinel never pollutes a finite prefix.
    float s_exc = __shfl_up(s, 1, 64);
    if (lane == 0) s_exc = 0.0f;

    // transmittance T_i = exp(-s_exc); weight = T_i * (1 - exp(-sd_i))
    const float e = __expf(-sd);          // exp(-1e10) -> 0, fine
    const float w = __expf(-s_exc) * (1.0f - e);

    // Feature loads: 12B/lane over a contiguous 768B span per ray
    const float* fp = rays_feature + (long)ray * (N_PTS * 3) + lane * 3;
    float wfx = w * fp[0];
    float wfy = w * fp[1];
    float wfz = w * fp[2];
    float wd  = w * d_i;

    // Butterfly reduce all four accumulators across the wave
    #pragma unroll
    for (int off = 32; off > 0; off >>= 1) {
        wfx += __shfl_xor(wfx, off, 64);
        wfy += __shfl_xor(wfy, off, 64);
        wfz += __shfl_xor(wfz, off, 64);
        wd  += __shfl_xor(wd,  off, 64);
    }

    if (lane == 0) {
        out[(long)ray * 3 + 0] = wfx;
        out[(long)ray * 3 + 1] = wfy;
        out[(long)ray * 3 + 2] = wfz;
        out[(long)N_RAYS * 3 + ray] = wd;
    }
}

extern "C" void kernel_launch(void* const* d_in, const int* in_sizes, int n_in,
                              void* d_out, int out_size, void* d_ws, size_t ws_size,
                              hipStream_t stream) {
    const float* density      = (const float*)d_in[0];
    const float* depth_values = (const float*)d_in[1];
    const float* rays_feature = (const float*)d_in[2];
    float* out = (float*)d_out;

    const int blocks = N_RAYS / RAYS_PER_BLOCK;  // 65536
    volume_render_kernel<<<blocks, 256, 0, stream>>>(
        density, depth_values, rays_feature, out);
}